// Round 3
// baseline (99.372 us; speedup 1.0000x reference)
//
#include <hip/hip_runtime.h>

#define BB 4096
#define II 512
#define HH 1024
#define RR 128

typedef __bf16 bf16x8 __attribute__((ext_vector_type(8)));
typedef float  f32x4  __attribute__((ext_vector_type(4)));
typedef unsigned short u16x8 __attribute__((ext_vector_type(8)));
typedef unsigned short u16x4 __attribute__((ext_vector_type(4)));

__device__ __forceinline__ unsigned short f2bf(float f) {
  unsigned int u = __float_as_uint(f);
  u += 0x7fffu + ((u >> 16) & 1u);   // round-to-nearest-even
  return (unsigned short)(u >> 16);
}
__device__ __forceinline__ float sigm(float v) { return 1.f / (1.f + __expf(-v)); }
__device__ __forceinline__ float tanh_f(float v) { return 1.f - 2.f / (1.f + __expf(2.f * v)); }

// ---------------- workspace layout (bytes) ----------------
// T   : 0        .. 2097152   bf16 [4096][256]   (stage1 out = [x@Ux , h@Uh])
// VC  : 2097152  .. 4194304   bf16 [4096][256]   wave-fragment-ordered V rows:
//        row r = jb*256 + w*32 + f*16 + c  ->  (gate g = f*2 + (c>>3),
//        j = jb*64 + w*8 + (c&7));  VC[r][k] = V_{x|h}[g*H + j][k]
// UTX : 4194304  .. 4325376   bf16 [128][512]    U_x^T
// UTH : 4325376  .. 4587520   bf16 [128][1024]   U_h^T
// CX  : 4587520  .. 4595712   f32  [4][512]      corr_x
// CH  : 4595712  .. 4612096   f32  [4][1024]     corr_h
// BC  : 4612096  .. 4628480   f32  [4096]        b_x + b_h

__global__ __launch_bounds__(256) void prep_kernel(
    const float* __restrict__ Ux, const float* __restrict__ Uh,
    const float* __restrict__ Vx, const float* __restrict__ Vh,
    const float* __restrict__ bx, const float* __restrict__ bh,
    unsigned short* __restrict__ VC, unsigned short* __restrict__ UTX,
    unsigned short* __restrict__ UTH, float* __restrict__ CX,
    float* __restrict__ CH, float* __restrict__ BC)
{
  int tid = blockIdx.x * 256 + threadIdx.x;
  if (tid < 131072) {                       // VC: fragment-ordered + bf16, 8 elems/thread
    int row = tid >> 5, kc = tid & 31, k = kc * 8;
    int jb = row >> 8;                      // 0..15 (64 j each)
    int t8 = row & 255;
    int w = t8 >> 5, f = (t8 >> 4) & 1, cc = t8 & 15;
    int g = f * 2 + (cc >> 3);
    int j = jb * 64 + w * 8 + (cc & 7);
    int vrow = g * HH + j;
    const float* src = (k < 128) ? (Vx + vrow * RR + k) : (Vh + vrow * RR + (k - 128));
    f32x4 a = *(const f32x4*)src;
    f32x4 b = *(const f32x4*)(src + 4);
    u16x8 o;
    o[0]=f2bf(a[0]); o[1]=f2bf(a[1]); o[2]=f2bf(a[2]); o[3]=f2bf(a[3]);
    o[4]=f2bf(b[0]); o[5]=f2bf(b[1]); o[6]=f2bf(b[2]); o[7]=f2bf(b[3]);
    *(u16x8*)(VC + row * 256 + k) = o;
  } else if (tid < 139264) {                // UTX: transpose U_x -> [n][k] bf16
    int idx = tid - 131072;
    int n = idx & 127, k = (idx >> 7) * 8;
    u16x8 o;
    #pragma unroll
    for (int e = 0; e < 8; ++e) o[e] = f2bf(Ux[(k + e) * RR + n]);
    *(u16x8*)(UTX + n * II + k) = o;
  } else if (tid < 155648) {                // UTH: transpose U_h -> [n][k] bf16
    int idx = tid - 139264;
    int n = idx & 127, k = (idx >> 7) * 8;
    u16x8 o;
    #pragma unroll
    for (int e = 0; e < 8; ++e) o[e] = f2bf(Uh[(k + e) * RR + n]);
    *(u16x8*)(UTH + n * HH + k) = o;
  } else if (tid < 157696) {                // corr_x[g][i]
    int idx = tid - 155648;
    int g = idx >> 9, i = idx & 511;
    const float* u = Ux + i * RR;
    const float* v = Vx + (g * HH + i) * RR;
    float s = 0.f;
    #pragma unroll 8
    for (int r4 = 0; r4 < 32; ++r4) {
      f32x4 uu = *(const f32x4*)(u + r4 * 4);
      f32x4 vv = *(const f32x4*)(v + r4 * 4);
      s += uu[0]*vv[0] + uu[1]*vv[1] + uu[2]*vv[2] + uu[3]*vv[3];
    }
    CX[g * II + i] = s;
  } else if (tid < 161792) {                // corr_h[g][j]
    int idx = tid - 157696;
    int g = idx >> 10, j = idx & 1023;
    const float* u = Uh + j * RR;
    const float* v = Vh + (g * HH + j) * RR;
    float s = 0.f;
    #pragma unroll 8
    for (int r4 = 0; r4 < 32; ++r4) {
      f32x4 uu = *(const f32x4*)(u + r4 * 4);
      f32x4 vv = *(const f32x4*)(v + r4 * 4);
      s += uu[0]*vv[0] + uu[1]*vv[1] + uu[2]*vv[2] + uu[3]*vv[3];
    }
    CH[g * HH + j] = s;
  } else if (tid < 165888) {                // combined bias
    int n = tid - 161792;
    BC[n] = bx[n] + bh[n];
  }
}

// ---- stage1: barrier-free K-split-across-waves thin GEMM ----
template<int K, int NKS>
__device__ __forceinline__ void s1_core(
    const float* __restrict__ src, const unsigned short* __restrict__ Ut,
    unsigned short* __restrict__ T, float* __restrict__ Red,
    int b0, int p, int t)
{
  int l = t & 63, w = t >> 6;
  int row = l & 15, kof = (l >> 4) * 8;
  int kc0 = w * (K / 4);
  const float* ap = src + (b0 + row) * K + kc0 + kof;
  const unsigned short* bp = Ut + row * K + kc0 + kof;

  f32x4 acc[8];
  #pragma unroll
  for (int fi = 0; fi < 8; ++fi) acc[fi] = (f32x4){0.f, 0.f, 0.f, 0.f};

  #pragma unroll
  for (int ks = 0; ks < NKS; ++ks) {
    f32x4 a0 = *(const f32x4*)(ap + ks * 32);
    f32x4 a1 = *(const f32x4*)(ap + ks * 32 + 4);
    union { bf16x8 v; unsigned short u[8]; } af;
    af.u[0]=f2bf(a0[0]); af.u[1]=f2bf(a0[1]); af.u[2]=f2bf(a0[2]); af.u[3]=f2bf(a0[3]);
    af.u[4]=f2bf(a1[0]); af.u[5]=f2bf(a1[1]); af.u[6]=f2bf(a1[2]); af.u[7]=f2bf(a1[3]);
    #pragma unroll
    for (int fi = 0; fi < 8; ++fi) {
      bf16x8 bf = *(const bf16x8*)(bp + fi * 16 * K + ks * 32);
      acc[fi] = __builtin_amdgcn_mfma_f32_16x16x32_bf16(af.v, bf, acc[fi], 0, 0, 0);
    }
  }

  #pragma unroll
  for (int fi = 0; fi < 8; ++fi) {
    int n = fi * 16 + row;
    #pragma unroll
    for (int reg = 0; reg < 4; ++reg) {
      int m = (l >> 4) * 4 + reg;
      Red[(w * 16 + m) * 132 + n] = acc[fi][reg];
    }
  }
  __syncthreads();

  #pragma unroll
  for (int it = 0; it < 2; ++it) {
    int q = it * 256 + t;
    int m = q >> 5, c4 = (q & 31) * 4;
    f32x4 s0 = *(const f32x4*)(Red + (0 * 16 + m) * 132 + c4);
    f32x4 s1 = *(const f32x4*)(Red + (1 * 16 + m) * 132 + c4);
    f32x4 s2 = *(const f32x4*)(Red + (2 * 16 + m) * 132 + c4);
    f32x4 s3 = *(const f32x4*)(Red + (3 * 16 + m) * 132 + c4);
    f32x4 s = s0 + s1 + s2 + s3;
    u16x4 o;
    o[0]=f2bf(s[0]); o[1]=f2bf(s[1]); o[2]=f2bf(s[2]); o[3]=f2bf(s[3]);
    *(u16x4*)(T + (b0 + m) * 256 + p * 128 + c4) = o;
  }
}

__global__ __launch_bounds__(256) void stage1_kernel(
    const float* __restrict__ x, const float* __restrict__ h,
    const unsigned short* __restrict__ UTX, const unsigned short* __restrict__ UTH,
    unsigned short* __restrict__ T)
{
  __shared__ alignas(16) float Red[4 * 16 * 132];
  int t = threadIdx.x;
  int mb = blockIdx.x & 255;
  if (blockIdx.x < 256) s1_core<II, II / 128>(x, UTX, T, Red, mb * 16, 0, t);
  else                  s1_core<HH, HH / 128>(h, UTH, T, Red, mb * 16, 1, t);
}

// ---- stage2 v3: zero-LDS, barrier-free. B (VC) fragments live in registers
// (2 frags x 8 ks = 64 VGPR/wave, loaded once); A streams from L2-resident T.
// Block = 128 rows x 64 j; 8 waves each own 8 j (all 4 gates). Grid 512,
// XCD-swizzled so each XCD's 2 jb-slabs of VC stay in its L2.
__global__ __launch_bounds__(512, 3) void stage2_kernel(
    const unsigned short* __restrict__ T, const unsigned short* __restrict__ VC,
    const float* __restrict__ CX, const float* __restrict__ CH, const float* __restrict__ BC,
    const float* __restrict__ x, const float* __restrict__ h, const float* __restrict__ c,
    const float* __restrict__ dx, const float* __restrict__ dh,
    float* __restrict__ out)
{
  int t = threadIdx.x, l = t & 63, w = t >> 6;
  int xcd = blockIdx.x & 7, idx = blockIdx.x >> 3;    // 512 = 8 xcd * 64
  int jb = xcd * 2 + (idx >> 5);                      // 0..15
  int mb = idx & 31;                                  // 0..31
  int b0 = mb * 128, j0 = jb * 64;
  int row = l & 15, hi = l >> 4;
  int koff = hi * 8;
  int ch = (l >> 3) & 1;
  int jv = j0 + w * 8 + (l & 7);
  bool has_x = (j0 < II);

  // B fragments: wave w covers VC rows jb*256 + w*32 + {0..31}
  const unsigned short* vp = VC + (jb * 256 + w * 32 + row) * 256 + koff;
  bf16x8 bf0[8], bf1[8];
  #pragma unroll
  for (int ks = 0; ks < 8; ++ks) {
    bf0[ks] = *(const bf16x8*)(vp + ks * 32);
    bf1[ks] = *(const bf16x8*)(vp + 16 * 256 + ks * 32);
  }

  // per-j constants (lane-fixed for the whole block)
  float dhv = dh[jv];
  float dxv = has_x ? dx[jv] : 0.f;
  float cxv0 = has_x ? CX[0 * II + jv] : 0.f;
  float cxv1 = has_x ? CX[1 * II + jv] : 0.f;
  float cxv2 = has_x ? CX[2 * II + jv] : 0.f;
  float cxv3 = has_x ? CX[3 * II + jv] : 0.f;
  float chv0 = CH[0 * HH + jv], chv1 = CH[1 * HH + jv];
  float chv2 = CH[2 * HH + jv], chv3 = CH[3 * HH + jv];
  float bcv0 = BC[0 * HH + jv], bcv1 = BC[1 * HH + jv];
  float bcv2 = BC[2 * HH + jv], bcv3 = BC[3 * HH + jv];

  const unsigned short* ap0 = T + (b0 + row) * 256 + koff;

  #pragma unroll 2
  for (int ms = 0; ms < 8; ++ms) {
    const unsigned short* ap = ap0 + ms * 16 * 256;
    f32x4 acc0 = (f32x4){0.f, 0.f, 0.f, 0.f};
    f32x4 acc1 = (f32x4){0.f, 0.f, 0.f, 0.f};
    #pragma unroll
    for (int ks = 0; ks < 8; ++ks) {
      bf16x8 a = *(const bf16x8*)(ap + ks * 32);
      acc0 = __builtin_amdgcn_mfma_f32_16x16x32_bf16(a, bf0[ks], acc0, 0, 0, 0);
      acc1 = __builtin_amdgcn_mfma_f32_16x16x32_bf16(a, bf1[ks], acc1, 0, 0, 0);
    }
    // epilogue: lane handles regs {ch*2, ch*2+1}; partner (l^8) has other 2 gates
    #pragma unroll
    for (int rr = 0; rr < 2; ++rr) {
      float keep0 = ch ? acc0[2 + rr] : acc0[rr];
      float send0 = ch ? acc0[rr] : acc0[2 + rr];
      float keep1 = ch ? acc1[2 + rr] : acc1[rr];
      float send1 = ch ? acc1[rr] : acc1[2 + rr];
      float recv0 = __shfl_xor(send0, 8);
      float recv1 = __shfl_xor(send1, 8);
      float p0 = ch ? recv0 : keep0;   // gate i
      float p1 = ch ? keep0 : recv0;   // gate f
      float p2 = ch ? recv1 : keep1;   // gate o
      float p3 = ch ? keep1 : recv1;   // gate n
      int b = b0 + ms * 16 + hi * 4 + ch * 2 + rr;
      float hv = h[b * HH + jv];
      float cv = c[b * HH + jv];
      float addv = dhv * hv;
      if (has_x) {
        float xv = x[b * II + jv];
        addv += dxv * xv;
        p0 -= xv * cxv0; p1 -= xv * cxv1; p2 -= xv * cxv2; p3 -= xv * cxv3;
      }
      p0 += bcv0 + addv - hv * chv0;
      p1 += bcv1 + addv - hv * chv1;
      p2 += bcv2 + addv - hv * chv2;
      p3 += bcv3 + addv - hv * chv3;
      float ig = sigm(p0);
      float fg = sigm(p1);
      float og = sigm(p2);
      float ng = tanh_f(p3);
      float cn = fg * cv + ig * ng;
      float hn = og * tanh_f(cn);
      out[b * HH + jv] = hn;
      out[BB * HH + b * HH + jv] = cn;
    }
  }
}

extern "C" void kernel_launch(void* const* d_in, const int* in_sizes, int n_in,
                              void* d_out, int out_size, void* d_ws, size_t ws_size,
                              hipStream_t stream) {
  const float* x  = (const float*)d_in[0];
  const float* h  = (const float*)d_in[1];
  const float* c  = (const float*)d_in[2];
  const float* Ux = (const float*)d_in[3];
  const float* Uh = (const float*)d_in[4];
  const float* Vx = (const float*)d_in[5];
  const float* Vh = (const float*)d_in[6];
  const float* bx = (const float*)d_in[7];
  const float* bh = (const float*)d_in[8];
  const float* dx = (const float*)d_in[9];
  const float* dh = (const float*)d_in[10];
  char* ws = (char*)d_ws;
  unsigned short* T   = (unsigned short*)(ws + 0);
  unsigned short* VC  = (unsigned short*)(ws + 2097152);
  unsigned short* UTX = (unsigned short*)(ws + 4194304);
  unsigned short* UTH = (unsigned short*)(ws + 4325376);
  float* CX = (float*)(ws + 4587520);
  float* CH = (float*)(ws + 4595712);
  float* BC = (float*)(ws + 4612096);
  float* out = (float*)d_out;

  prep_kernel<<<648, 256, 0, stream>>>(Ux, Uh, Vx, Vh, bx, bh, VC, UTX, UTH, CX, CH, BC);
  stage1_kernel<<<512, 256, 0, stream>>>(x, h, UTX, UTH, T);
  stage2_kernel<<<512, 512, 0, stream>>>(T, VC, CX, CH, BC, x, h, c, dx, dh, out);
}

// Round 4
// 70.019 us; speedup vs baseline: 1.4192x; 1.4192x over previous
//
#include <hip/hip_runtime.h>

#define BB 4096
#define II 512
#define HH 1024
#define RR 128

typedef __bf16 bf16x8 __attribute__((ext_vector_type(8)));
typedef float  f32x4  __attribute__((ext_vector_type(4)));
typedef unsigned short u16x8 __attribute__((ext_vector_type(8)));
typedef unsigned short u16x4 __attribute__((ext_vector_type(4)));

__device__ __forceinline__ unsigned short f2bf(float f) {
  unsigned int u = __float_as_uint(f);
  u += 0x7fffu + ((u >> 16) & 1u);   // round-to-nearest-even
  return (unsigned short)(u >> 16);
}
__device__ __forceinline__ float sigm(float v) { return 1.f / (1.f + __expf(-v)); }
__device__ __forceinline__ float tanh_f(float v) { return 1.f - 2.f / (1.f + __expf(2.f * v)); }

// ---------------- workspace layout (bytes) ----------------
// T   : 0        .. 2097152   bf16 [4096][256]   (stage1 out = [x@Ux , h@Uh])
// VC  : 2097152  .. 4194304   bf16 [4096][256]   wave-fragment-ordered V rows:
//        row r = jb*128 + w*32 + f*16 + c  ->  (gate g = f*2 + (c>>3),
//        j = jb*32 + w*8 + (c&7));  VC[r][k] = V_{x|h}[g*H + j][k]
// UTX : 4194304  .. 4325376   bf16 [128][512]    U_x^T
// UTH : 4325376  .. 4587520   bf16 [128][1024]   U_h^T
// CX  : 4587520  .. 4595712   f32  [4][512]      corr_x
// CH  : 4595712  .. 4612096   f32  [4][1024]     corr_h
// BC  : 4612096  .. 4628480   f32  [4096]        b_x + b_h

__global__ __launch_bounds__(256) void prep_kernel(
    const float* __restrict__ Ux, const float* __restrict__ Uh,
    const float* __restrict__ Vx, const float* __restrict__ Vh,
    const float* __restrict__ bx, const float* __restrict__ bh,
    unsigned short* __restrict__ VC, unsigned short* __restrict__ UTX,
    unsigned short* __restrict__ UTH, float* __restrict__ CX,
    float* __restrict__ CH, float* __restrict__ BC)
{
  int tid = blockIdx.x * 256 + threadIdx.x;
  if (tid < 131072) {                       // VC: fragment-ordered + bf16, 8 elems/thread
    int row = tid >> 5, kc = tid & 31, k = kc * 8;
    int jb = row >> 7;                      // 0..31 (32 j each)
    int t7 = row & 127;
    int w = t7 >> 5, f = (t7 >> 4) & 1, cc = t7 & 15;
    int g = f * 2 + (cc >> 3);
    int j = jb * 32 + w * 8 + (cc & 7);
    int vrow = g * HH + j;
    const float* src = (k < 128) ? (Vx + vrow * RR + k) : (Vh + vrow * RR + (k - 128));
    f32x4 a = *(const f32x4*)src;
    f32x4 b = *(const f32x4*)(src + 4);
    u16x8 o;
    o[0]=f2bf(a[0]); o[1]=f2bf(a[1]); o[2]=f2bf(a[2]); o[3]=f2bf(a[3]);
    o[4]=f2bf(b[0]); o[5]=f2bf(b[1]); o[6]=f2bf(b[2]); o[7]=f2bf(b[3]);
    *(u16x8*)(VC + row * 256 + k) = o;
  } else if (tid < 139264) {                // UTX: transpose U_x -> [n][k] bf16
    int idx = tid - 131072;
    int n = idx & 127, k = (idx >> 7) * 8;
    u16x8 o;
    #pragma unroll
    for (int e = 0; e < 8; ++e) o[e] = f2bf(Ux[(k + e) * RR + n]);
    *(u16x8*)(UTX + n * II + k) = o;
  } else if (tid < 155648) {                // UTH: transpose U_h -> [n][k] bf16
    int idx = tid - 139264;
    int n = idx & 127, k = (idx >> 7) * 8;
    u16x8 o;
    #pragma unroll
    for (int e = 0; e < 8; ++e) o[e] = f2bf(Uh[(k + e) * RR + n]);
    *(u16x8*)(UTH + n * HH + k) = o;
  } else if (tid < 157696) {                // corr_x[g][i]
    int idx = tid - 155648;
    int g = idx >> 9, i = idx & 511;
    const float* u = Ux + i * RR;
    const float* v = Vx + (g * HH + i) * RR;
    float s = 0.f;
    #pragma unroll 8
    for (int r4 = 0; r4 < 32; ++r4) {
      f32x4 uu = *(const f32x4*)(u + r4 * 4);
      f32x4 vv = *(const f32x4*)(v + r4 * 4);
      s += uu[0]*vv[0] + uu[1]*vv[1] + uu[2]*vv[2] + uu[3]*vv[3];
    }
    CX[g * II + i] = s;
  } else if (tid < 161792) {                // corr_h[g][j]
    int idx = tid - 157696;
    int g = idx >> 10, j = idx & 1023;
    const float* u = Uh + j * RR;
    const float* v = Vh + (g * HH + j) * RR;
    float s = 0.f;
    #pragma unroll 8
    for (int r4 = 0; r4 < 32; ++r4) {
      f32x4 uu = *(const f32x4*)(u + r4 * 4);
      f32x4 vv = *(const f32x4*)(v + r4 * 4);
      s += uu[0]*vv[0] + uu[1]*vv[1] + uu[2]*vv[2] + uu[3]*vv[3];
    }
    CH[g * HH + j] = s;
  } else if (tid < 165888) {                // combined bias
    int n = tid - 161792;
    BC[n] = bx[n] + bh[n];
  }
}

// ---- stage1: barrier-free K-split-across-waves thin GEMM (unchanged) ----
template<int K, int NKS>
__device__ __forceinline__ void s1_core(
    const float* __restrict__ src, const unsigned short* __restrict__ Ut,
    unsigned short* __restrict__ T, float* __restrict__ Red,
    int b0, int p, int t)
{
  int l = t & 63, w = t >> 6;
  int row = l & 15, kof = (l >> 4) * 8;
  int kc0 = w * (K / 4);
  const float* ap = src + (b0 + row) * K + kc0 + kof;
  const unsigned short* bp = Ut + row * K + kc0 + kof;

  f32x4 acc[8];
  #pragma unroll
  for (int fi = 0; fi < 8; ++fi) acc[fi] = (f32x4){0.f, 0.f, 0.f, 0.f};

  #pragma unroll
  for (int ks = 0; ks < NKS; ++ks) {
    f32x4 a0 = *(const f32x4*)(ap + ks * 32);
    f32x4 a1 = *(const f32x4*)(ap + ks * 32 + 4);
    union { bf16x8 v; unsigned short u[8]; } af;
    af.u[0]=f2bf(a0[0]); af.u[1]=f2bf(a0[1]); af.u[2]=f2bf(a0[2]); af.u[3]=f2bf(a0[3]);
    af.u[4]=f2bf(a1[0]); af.u[5]=f2bf(a1[1]); af.u[6]=f2bf(a1[2]); af.u[7]=f2bf(a1[3]);
    #pragma unroll
    for (int fi = 0; fi < 8; ++fi) {
      bf16x8 bf = *(const bf16x8*)(bp + fi * 16 * K + ks * 32);
      acc[fi] = __builtin_amdgcn_mfma_f32_16x16x32_bf16(af.v, bf, acc[fi], 0, 0, 0);
    }
  }

  #pragma unroll
  for (int fi = 0; fi < 8; ++fi) {
    int n = fi * 16 + row;
    #pragma unroll
    for (int reg = 0; reg < 4; ++reg) {
      int m = (l >> 4) * 4 + reg;
      Red[(w * 16 + m) * 132 + n] = acc[fi][reg];
    }
  }
  __syncthreads();

  #pragma unroll
  for (int it = 0; it < 2; ++it) {
    int q = it * 256 + t;
    int m = q >> 5, c4 = (q & 31) * 4;
    f32x4 s0 = *(const f32x4*)(Red + (0 * 16 + m) * 132 + c4);
    f32x4 s1 = *(const f32x4*)(Red + (1 * 16 + m) * 132 + c4);
    f32x4 s2 = *(const f32x4*)(Red + (2 * 16 + m) * 132 + c4);
    f32x4 s3 = *(const f32x4*)(Red + (3 * 16 + m) * 132 + c4);
    f32x4 s = s0 + s1 + s2 + s3;
    u16x4 o;
    o[0]=f2bf(s[0]); o[1]=f2bf(s[1]); o[2]=f2bf(s[2]); o[3]=f2bf(s[3]);
    *(u16x4*)(T + (b0 + m) * 256 + p * 128 + c4) = o;
  }
}

__global__ __launch_bounds__(256) void stage1_kernel(
    const float* __restrict__ x, const float* __restrict__ h,
    const unsigned short* __restrict__ UTX, const unsigned short* __restrict__ UTH,
    unsigned short* __restrict__ T)
{
  __shared__ alignas(16) float Red[4 * 16 * 132];
  int t = threadIdx.x;
  int mb = blockIdx.x & 255;
  if (blockIdx.x < 256) s1_core<II, II / 128>(x, UTX, T, Red, mb * 16, 0, t);
  else                  s1_core<HH, HH / 128>(h, UTH, T, Red, mb * 16, 1, t);
}

// ---- stage2 v4: B (VC) in registers (64 VGPR/wave, loaded once from L2),
// A-tile (64 rows x K=256) in 32 KB LDS via global_load_lds width-16 with
// XOR-swizzled GLOBAL source (linear LDS dest) -> conflict-free ds_read_b128.
// Block = 64 rows x 32 j, 256 thr (4 waves, each owns 8 j = all 4 gates).
// One barrier. Grid 2048, jb->XCD binding (VC slab + T L2-resident).
__global__ __launch_bounds__(256, 3) void stage2_kernel(
    const unsigned short* __restrict__ T, const unsigned short* __restrict__ VC,
    const float* __restrict__ CX, const float* __restrict__ CH, const float* __restrict__ BC,
    const float* __restrict__ x, const float* __restrict__ h, const float* __restrict__ c,
    const float* __restrict__ dx, const float* __restrict__ dh,
    float* __restrict__ out)
{
  __shared__ alignas(16) unsigned short As[64 * 256];   // 32 KB, granule-swizzled
  int t = threadIdx.x, l = t & 63, w = t >> 6;
  int xcd = blockIdx.x & 7, bi = blockIdx.x >> 3;       // 2048 = 8 xcd * 4 jb * 64 mb
  int jb = xcd * 4 + (bi >> 6);
  int mb = bi & 63;
  int b0 = mb * 64, j0 = jb * 32;
  int r16 = l & 15, hi = l >> 4;
  int koff = hi * 8;
  int ch = (l >> 3) & 1;
  int jv = j0 + w * 8 + (l & 7);
  bool has_x = (j0 < II);

  // issue A staging first: LDS granule G holds T granule (row, gl^(row&7))
  #pragma unroll
  for (int p = 0; p < 8; ++p) {
    int G = p * 256 + t;
    int r = G >> 5, gl = G & 31;
    int gs = gl ^ (r & 7);
    const unsigned short* gp = T + (b0 + r) * 256 + gs * 8;
    __builtin_amdgcn_global_load_lds(
        (const __attribute__((address_space(1))) void*)gp,
        (__attribute__((address_space(3))) void*)(As + G * 8), 16, 0, 0);
  }

  // B fragments: wave w covers VC rows jb*128 + w*32 + {0..31}
  const unsigned short* vp = VC + (jb * 128 + w * 32 + r16) * 256 + koff;
  bf16x8 bf0[8], bf1[8];
  #pragma unroll
  for (int ks = 0; ks < 8; ++ks) {
    bf0[ks] = *(const bf16x8*)(vp + ks * 32);
    bf1[ks] = *(const bf16x8*)(vp + 16 * 256 + ks * 32);
  }

  // per-j constants (lane-fixed)
  float dhv = dh[jv];
  float dxv = has_x ? dx[jv] : 0.f;
  float cxv0 = has_x ? CX[0 * II + jv] : 0.f;
  float cxv1 = has_x ? CX[1 * II + jv] : 0.f;
  float cxv2 = has_x ? CX[2 * II + jv] : 0.f;
  float cxv3 = has_x ? CX[3 * II + jv] : 0.f;
  float chv0 = CH[0 * HH + jv], chv1 = CH[1 * HH + jv];
  float chv2 = CH[2 * HH + jv], chv3 = CH[3 * HH + jv];
  float bcv0 = BC[0 * HH + jv], bcv1 = BC[1 * HH + jv];
  float bcv2 = BC[2 * HH + jv], bcv3 = BC[3 * HH + jv];

  asm volatile("s_waitcnt vmcnt(0)" ::: "memory");
  __syncthreads();

  const char* Ab = (const char*)As;
  int rbase = r16 * 512;

  #pragma unroll
  for (int rf = 0; rf < 4; ++rf) {
    f32x4 acc0 = (f32x4){0.f, 0.f, 0.f, 0.f};
    f32x4 acc1 = (f32x4){0.f, 0.f, 0.f, 0.f};
    #pragma unroll
    for (int ks = 0; ks < 8; ++ks) {
      int gsw = ((ks * 4 + hi) ^ (r16 & 7)) * 16;
      bf16x8 a = *(const bf16x8*)(Ab + rf * 8192 + rbase + gsw);
      acc0 = __builtin_amdgcn_mfma_f32_16x16x32_bf16(a, bf0[ks], acc0, 0, 0, 0);
      acc1 = __builtin_amdgcn_mfma_f32_16x16x32_bf16(a, bf1[ks], acc1, 0, 0, 0);
    }
    // epilogue: lane handles regs {ch*2, ch*2+1}; partner (l^8) has other 2 gates
    #pragma unroll
    for (int rr = 0; rr < 2; ++rr) {
      float keep0 = ch ? acc0[2 + rr] : acc0[rr];
      float send0 = ch ? acc0[rr] : acc0[2 + rr];
      float keep1 = ch ? acc1[2 + rr] : acc1[rr];
      float send1 = ch ? acc1[rr] : acc1[2 + rr];
      float recv0 = __shfl_xor(send0, 8);
      float recv1 = __shfl_xor(send1, 8);
      float p0 = ch ? recv0 : keep0;   // gate i
      float p1 = ch ? keep0 : recv0;   // gate f
      float p2 = ch ? recv1 : keep1;   // gate o
      float p3 = ch ? keep1 : recv1;   // gate n
      int b = b0 + rf * 16 + hi * 4 + ch * 2 + rr;
      float hv = h[b * HH + jv];
      float cv = c[b * HH + jv];
      float addv = dhv * hv;
      if (has_x) {
        float xv = x[b * II + jv];
        addv += dxv * xv;
        p0 -= xv * cxv0; p1 -= xv * cxv1; p2 -= xv * cxv2; p3 -= xv * cxv3;
      }
      p0 += bcv0 + addv - hv * chv0;
      p1 += bcv1 + addv - hv * chv1;
      p2 += bcv2 + addv - hv * chv2;
      p3 += bcv3 + addv - hv * chv3;
      float ig = sigm(p0);
      float fg = sigm(p1);
      float og = sigm(p2);
      float ng = tanh_f(p3);
      float cn = fg * cv + ig * ng;
      float hn = og * tanh_f(cn);
      out[b * HH + jv] = hn;
      out[BB * HH + b * HH + jv] = cn;
    }
  }
}

extern "C" void kernel_launch(void* const* d_in, const int* in_sizes, int n_in,
                              void* d_out, int out_size, void* d_ws, size_t ws_size,
                              hipStream_t stream) {
  const float* x  = (const float*)d_in[0];
  const float* h  = (const float*)d_in[1];
  const float* c  = (const float*)d_in[2];
  const float* Ux = (const float*)d_in[3];
  const float* Uh = (const float*)d_in[4];
  const float* Vx = (const float*)d_in[5];
  const float* Vh = (const float*)d_in[6];
  const float* bx = (const float*)d_in[7];
  const float* bh = (const float*)d_in[8];
  const float* dx = (const float*)d_in[9];
  const float* dh = (const float*)d_in[10];
  char* ws = (char*)d_ws;
  unsigned short* T   = (unsigned short*)(ws + 0);
  unsigned short* VC  = (unsigned short*)(ws + 2097152);
  unsigned short* UTX = (unsigned short*)(ws + 4194304);
  unsigned short* UTH = (unsigned short*)(ws + 4325376);
  float* CX = (float*)(ws + 4587520);
  float* CH = (float*)(ws + 4595712);
  float* BC = (float*)(ws + 4612096);
  float* out = (float*)d_out;

  prep_kernel<<<648, 256, 0, stream>>>(Ux, Uh, Vx, Vh, bx, bh, VC, UTX, UTH, CX, CH, BC);
  stage1_kernel<<<512, 256, 0, stream>>>(x, h, UTX, UTH, T);
  stage2_kernel<<<2048, 256, 0, stream>>>(T, VC, CX, CH, BC, x, h, c, dx, dh, out);
}

// Round 5
// 65.406 us; speedup vs baseline: 1.5193x; 1.0705x over previous
//
#include <hip/hip_runtime.h>

#define BB 4096
#define II 512
#define HH 1024
#define RR 128

typedef __bf16 bf16x8 __attribute__((ext_vector_type(8)));
typedef float  f32x4  __attribute__((ext_vector_type(4)));
typedef unsigned short u16x8 __attribute__((ext_vector_type(8)));
typedef unsigned short u16x4 __attribute__((ext_vector_type(4)));

__device__ __forceinline__ unsigned short f2bf(float f) {
  unsigned int u = __float_as_uint(f);
  u += 0x7fffu + ((u >> 16) & 1u);   // round-to-nearest-even
  return (unsigned short)(u >> 16);
}
__device__ __forceinline__ float sigm(float v) { return 1.f / (1.f + __expf(-v)); }
__device__ __forceinline__ float tanh_f(float v) { return 1.f - 2.f / (1.f + __expf(2.f * v)); }

// ---------------- workspace layout (bytes) ----------------
// T   : 0        .. 2097152   bf16 [4096][256]   (stage1 out = [x@Ux , h@Uh])
// VC  : 2097152  .. 4194304   bf16 [4096][256]   wave-fragment-ordered V rows:
//        row r = jb*128 + w*32 + f*16 + c  ->  (gate g = f*2 + (c>>3),
//        j = jb*32 + w*8 + (c&7));  VC[r][k] = V_{x|h}[g*H + j][k]
// UTX : 4194304  .. 4325376   bf16 [128][512]    U_x^T
// UTH : 4325376  .. 4587520   bf16 [128][1024]   U_h^T
// CX  : 4587520  .. 4595712   f32  [4][512]      corr_x
// CH  : 4595712  .. 4612096   f32  [4][1024]     corr_h
// BC  : 4612096  .. 4628480   f32  [4096]        b_x + b_h

__global__ __launch_bounds__(256) void prep_kernel(
    const float* __restrict__ Ux, const float* __restrict__ Uh,
    const float* __restrict__ Vx, const float* __restrict__ Vh,
    const float* __restrict__ bx, const float* __restrict__ bh,
    unsigned short* __restrict__ VC, unsigned short* __restrict__ UTX,
    unsigned short* __restrict__ UTH, float* __restrict__ CX,
    float* __restrict__ CH, float* __restrict__ BC)
{
  int tid = blockIdx.x * 256 + threadIdx.x;
  if (tid < 131072) {                       // VC: fragment-ordered + bf16, 8 elems/thread
    int row = tid >> 5, kc = tid & 31, k = kc * 8;
    int jb = row >> 7;                      // 0..31 (32 j each)
    int t7 = row & 127;
    int w = t7 >> 5, f = (t7 >> 4) & 1, cc = t7 & 15;
    int g = f * 2 + (cc >> 3);
    int j = jb * 32 + w * 8 + (cc & 7);
    int vrow = g * HH + j;
    const float* src = (k < 128) ? (Vx + vrow * RR + k) : (Vh + vrow * RR + (k - 128));
    f32x4 a = *(const f32x4*)src;
    f32x4 b = *(const f32x4*)(src + 4);
    u16x8 o;
    o[0]=f2bf(a[0]); o[1]=f2bf(a[1]); o[2]=f2bf(a[2]); o[3]=f2bf(a[3]);
    o[4]=f2bf(b[0]); o[5]=f2bf(b[1]); o[6]=f2bf(b[2]); o[7]=f2bf(b[3]);
    *(u16x8*)(VC + row * 256 + k) = o;
  } else if (tid < 139264) {                // UTX: transpose U_x -> [n][k] bf16
    int idx = tid - 131072;
    int n = idx & 127, k = (idx >> 7) * 8;
    u16x8 o;
    #pragma unroll
    for (int e = 0; e < 8; ++e) o[e] = f2bf(Ux[(k + e) * RR + n]);
    *(u16x8*)(UTX + n * II + k) = o;
  } else if (tid < 155648) {                // UTH: transpose U_h -> [n][k] bf16
    int idx = tid - 139264;
    int n = idx & 127, k = (idx >> 7) * 8;
    u16x8 o;
    #pragma unroll
    for (int e = 0; e < 8; ++e) o[e] = f2bf(Uh[(k + e) * RR + n]);
    *(u16x8*)(UTH + n * HH + k) = o;
  } else if (tid < 157696) {                // corr_x[g][i]
    int idx = tid - 155648;
    int g = idx >> 9, i = idx & 511;
    const float* u = Ux + i * RR;
    const float* v = Vx + (g * HH + i) * RR;
    float s = 0.f;
    #pragma unroll 8
    for (int r4 = 0; r4 < 32; ++r4) {
      f32x4 uu = *(const f32x4*)(u + r4 * 4);
      f32x4 vv = *(const f32x4*)(v + r4 * 4);
      s += uu[0]*vv[0] + uu[1]*vv[1] + uu[2]*vv[2] + uu[3]*vv[3];
    }
    CX[g * II + i] = s;
  } else if (tid < 161792) {                // corr_h[g][j]
    int idx = tid - 157696;
    int g = idx >> 10, j = idx & 1023;
    const float* u = Uh + j * RR;
    const float* v = Vh + (g * HH + j) * RR;
    float s = 0.f;
    #pragma unroll 8
    for (int r4 = 0; r4 < 32; ++r4) {
      f32x4 uu = *(const f32x4*)(u + r4 * 4);
      f32x4 vv = *(const f32x4*)(v + r4 * 4);
      s += uu[0]*vv[0] + uu[1]*vv[1] + uu[2]*vv[2] + uu[3]*vv[3];
    }
    CH[g * HH + j] = s;
  } else if (tid < 165888) {                // combined bias
    int n = tid - 161792;
    BC[n] = bx[n] + bh[n];
  }
}

// ---- stage1: barrier-free K-split-across-waves thin GEMM (unchanged) ----
template<int K, int NKS>
__device__ __forceinline__ void s1_core(
    const float* __restrict__ src, const unsigned short* __restrict__ Ut,
    unsigned short* __restrict__ T, float* __restrict__ Red,
    int b0, int p, int t)
{
  int l = t & 63, w = t >> 6;
  int row = l & 15, kof = (l >> 4) * 8;
  int kc0 = w * (K / 4);
  const float* ap = src + (b0 + row) * K + kc0 + kof;
  const unsigned short* bp = Ut + row * K + kc0 + kof;

  f32x4 acc[8];
  #pragma unroll
  for (int fi = 0; fi < 8; ++fi) acc[fi] = (f32x4){0.f, 0.f, 0.f, 0.f};

  #pragma unroll
  for (int ks = 0; ks < NKS; ++ks) {
    f32x4 a0 = *(const f32x4*)(ap + ks * 32);
    f32x4 a1 = *(const f32x4*)(ap + ks * 32 + 4);
    union { bf16x8 v; unsigned short u[8]; } af;
    af.u[0]=f2bf(a0[0]); af.u[1]=f2bf(a0[1]); af.u[2]=f2bf(a0[2]); af.u[3]=f2bf(a0[3]);
    af.u[4]=f2bf(a1[0]); af.u[5]=f2bf(a1[1]); af.u[6]=f2bf(a1[2]); af.u[7]=f2bf(a1[3]);
    #pragma unroll
    for (int fi = 0; fi < 8; ++fi) {
      bf16x8 bf = *(const bf16x8*)(bp + fi * 16 * K + ks * 32);
      acc[fi] = __builtin_amdgcn_mfma_f32_16x16x32_bf16(af.v, bf, acc[fi], 0, 0, 0);
    }
  }

  #pragma unroll
  for (int fi = 0; fi < 8; ++fi) {
    int n = fi * 16 + row;
    #pragma unroll
    for (int reg = 0; reg < 4; ++reg) {
      int m = (l >> 4) * 4 + reg;
      Red[(w * 16 + m) * 132 + n] = acc[fi][reg];
    }
  }
  __syncthreads();

  #pragma unroll
  for (int it = 0; it < 2; ++it) {
    int q = it * 256 + t;
    int m = q >> 5, c4 = (q & 31) * 4;
    f32x4 s0 = *(const f32x4*)(Red + (0 * 16 + m) * 132 + c4);
    f32x4 s1 = *(const f32x4*)(Red + (1 * 16 + m) * 132 + c4);
    f32x4 s2 = *(const f32x4*)(Red + (2 * 16 + m) * 132 + c4);
    f32x4 s3 = *(const f32x4*)(Red + (3 * 16 + m) * 132 + c4);
    f32x4 s = s0 + s1 + s2 + s3;
    u16x4 o;
    o[0]=f2bf(s[0]); o[1]=f2bf(s[1]); o[2]=f2bf(s[2]); o[3]=f2bf(s[3]);
    *(u16x4*)(T + (b0 + m) * 256 + p * 128 + c4) = o;
  }
}

__global__ __launch_bounds__(256) void stage1_kernel(
    const float* __restrict__ x, const float* __restrict__ h,
    const unsigned short* __restrict__ UTX, const unsigned short* __restrict__ UTH,
    unsigned short* __restrict__ T)
{
  __shared__ alignas(16) float Red[4 * 16 * 132];
  int t = threadIdx.x;
  int mb = blockIdx.x & 255;
  if (blockIdx.x < 256) s1_core<II, II / 128>(x, UTX, T, Red, mb * 16, 0, t);
  else                  s1_core<HH, HH / 128>(h, UTH, T, Red, mb * 16, 1, t);
}

// ---- stage2 v5: as v4 but ALL epilogue operands (h,c,x) prefetched into
// registers at block start (T14 async-split) so the MFMA+epilogue loop has
// zero load stalls. No occupancy cap -> regalloc may hold ~150 VGPR.
__global__ __launch_bounds__(256) void stage2_kernel(
    const unsigned short* __restrict__ T, const unsigned short* __restrict__ VC,
    const float* __restrict__ CX, const float* __restrict__ CH, const float* __restrict__ BC,
    const float* __restrict__ x, const float* __restrict__ h, const float* __restrict__ c,
    const float* __restrict__ dx, const float* __restrict__ dh,
    float* __restrict__ out)
{
  __shared__ alignas(16) unsigned short As[64 * 256];   // 32 KB, granule-swizzled
  int t = threadIdx.x, l = t & 63, w = t >> 6;
  int xcd = blockIdx.x & 7, bi = blockIdx.x >> 3;       // 2048 = 8 xcd * 4 jb * 64 mb
  int jb = xcd * 4 + (bi >> 6);
  int mb = bi & 63;
  int b0 = mb * 64, j0 = jb * 32;
  int r16 = l & 15, hi = l >> 4;
  int koff = hi * 8;
  int ch = (l >> 3) & 1;
  int jv = j0 + w * 8 + (l & 7);
  bool has_x = (j0 < II);

  // 1) issue A staging: LDS granule G holds T granule (row, gl^(row&7))
  #pragma unroll
  for (int p = 0; p < 8; ++p) {
    int G = p * 256 + t;
    int r = G >> 5, gl = G & 31;
    int gs = gl ^ (r & 7);
    const unsigned short* gp = T + (b0 + r) * 256 + gs * 8;
    __builtin_amdgcn_global_load_lds(
        (const __attribute__((address_space(1))) void*)gp,
        (__attribute__((address_space(3))) void*)(As + G * 8), 16, 0, 0);
  }

  // 2) prefetch ALL epilogue operands into registers (latency hides under
  //    staging + B-load + MFMA). Indices are fully static after unroll.
  float hv[8], cv[8], xv[8];
  #pragma unroll
  for (int rf = 0; rf < 4; ++rf)
    #pragma unroll
    for (int rr = 0; rr < 2; ++rr) {
      int q = rf * 2 + rr;
      int b = b0 + rf * 16 + hi * 4 + ch * 2 + rr;
      hv[q] = h[b * HH + jv];
      cv[q] = c[b * HH + jv];
      xv[q] = has_x ? x[b * II + jv] : 0.f;
    }

  // 3) B fragments: wave w covers VC rows jb*128 + w*32 + {0..31}
  const unsigned short* vp = VC + (jb * 128 + w * 32 + r16) * 256 + koff;
  bf16x8 bf0[8], bf1[8];
  #pragma unroll
  for (int ks = 0; ks < 8; ++ks) {
    bf0[ks] = *(const bf16x8*)(vp + ks * 32);
    bf1[ks] = *(const bf16x8*)(vp + 16 * 256 + ks * 32);
  }

  // 4) per-j constants (lane-fixed)
  float dhv = dh[jv];
  float dxv = has_x ? dx[jv] : 0.f;
  float cxv0 = has_x ? CX[0 * II + jv] : 0.f;
  float cxv1 = has_x ? CX[1 * II + jv] : 0.f;
  float cxv2 = has_x ? CX[2 * II + jv] : 0.f;
  float cxv3 = has_x ? CX[3 * II + jv] : 0.f;
  float chv0 = CH[0 * HH + jv], chv1 = CH[1 * HH + jv];
  float chv2 = CH[2 * HH + jv], chv3 = CH[3 * HH + jv];
  float bcv0 = BC[0 * HH + jv], bcv1 = BC[1 * HH + jv];
  float bcv2 = BC[2 * HH + jv], bcv3 = BC[3 * HH + jv];

  asm volatile("s_waitcnt vmcnt(0)" ::: "memory");
  __syncthreads();

  const char* Ab = (const char*)As;
  int rbase = r16 * 512;

  #pragma unroll
  for (int rf = 0; rf < 4; ++rf) {
    f32x4 acc0 = (f32x4){0.f, 0.f, 0.f, 0.f};
    f32x4 acc1 = (f32x4){0.f, 0.f, 0.f, 0.f};
    #pragma unroll
    for (int ks = 0; ks < 8; ++ks) {
      int gsw = ((ks * 4 + hi) ^ (r16 & 7)) * 16;
      bf16x8 a = *(const bf16x8*)(Ab + rf * 8192 + rbase + gsw);
      acc0 = __builtin_amdgcn_mfma_f32_16x16x32_bf16(a, bf0[ks], acc0, 0, 0, 0);
      acc1 = __builtin_amdgcn_mfma_f32_16x16x32_bf16(a, bf1[ks], acc1, 0, 0, 0);
    }
    // epilogue: lane handles regs {ch*2, ch*2+1}; partner (l^8) has other 2 gates
    #pragma unroll
    for (int rr = 0; rr < 2; ++rr) {
      int q = rf * 2 + rr;
      float keep0 = ch ? acc0[2 + rr] : acc0[rr];
      float send0 = ch ? acc0[rr] : acc0[2 + rr];
      float keep1 = ch ? acc1[2 + rr] : acc1[rr];
      float send1 = ch ? acc1[rr] : acc1[2 + rr];
      float recv0 = __shfl_xor(send0, 8);
      float recv1 = __shfl_xor(send1, 8);
      float p0 = ch ? recv0 : keep0;   // gate i
      float p1 = ch ? keep0 : recv0;   // gate f
      float p2 = ch ? recv1 : keep1;   // gate o
      float p3 = ch ? keep1 : recv1;   // gate n
      int b = b0 + rf * 16 + hi * 4 + ch * 2 + rr;
      float hvq = hv[q], cvq = cv[q];
      float addv = dhv * hvq;
      if (has_x) {
        float xvq = xv[q];
        addv += dxv * xvq;
        p0 -= xvq * cxv0; p1 -= xvq * cxv1; p2 -= xvq * cxv2; p3 -= xvq * cxv3;
      }
      p0 += bcv0 + addv - hvq * chv0;
      p1 += bcv1 + addv - hvq * chv1;
      p2 += bcv2 + addv - hvq * chv2;
      p3 += bcv3 + addv - hvq * chv3;
      float ig = sigm(p0);
      float fg = sigm(p1);
      float og = sigm(p2);
      float ng = tanh_f(p3);
      float cn = fg * cvq + ig * ng;
      float hn = og * tanh_f(cn);
      out[b * HH + jv] = hn;
      out[BB * HH + b * HH + jv] = cn;
    }
  }
}

extern "C" void kernel_launch(void* const* d_in, const int* in_sizes, int n_in,
                              void* d_out, int out_size, void* d_ws, size_t ws_size,
                              hipStream_t stream) {
  const float* x  = (const float*)d_in[0];
  const float* h  = (const float*)d_in[1];
  const float* c  = (const float*)d_in[2];
  const float* Ux = (const float*)d_in[3];
  const float* Uh = (const float*)d_in[4];
  const float* Vx = (const float*)d_in[5];
  const float* Vh = (const float*)d_in[6];
  const float* bx = (const float*)d_in[7];
  const float* bh = (const float*)d_in[8];
  const float* dx = (const float*)d_in[9];
  const float* dh = (const float*)d_in[10];
  char* ws = (char*)d_ws;
  unsigned short* T   = (unsigned short*)(ws + 0);
  unsigned short* VC  = (unsigned short*)(ws + 2097152);
  unsigned short* UTX = (unsigned short*)(ws + 4194304);
  unsigned short* UTH = (unsigned short*)(ws + 4325376);
  float* CX = (float*)(ws + 4587520);
  float* CH = (float*)(ws + 4595712);
  float* BC = (float*)(ws + 4612096);
  float* out = (float*)d_out;

  prep_kernel<<<648, 256, 0, stream>>>(Ux, Uh, Vx, Vh, bx, bh, VC, UTX, UTH, CX, CH, BC);
  stage1_kernel<<<512, 256, 0, stream>>>(x, h, UTX, UTH, T);
  stage2_kernel<<<2048, 256, 0, stream>>>(T, VC, CX, CH, BC, x, h, c, dx, dh, out);
}

// Round 6
// 62.367 us; speedup vs baseline: 1.5933x; 1.0487x over previous
//
#include <hip/hip_runtime.h>

#define BB 4096
#define II 512
#define HH 1024
#define RR 128

typedef __bf16 bf16x8 __attribute__((ext_vector_type(8)));
typedef float  f32x4  __attribute__((ext_vector_type(4)));
typedef unsigned short u16x8 __attribute__((ext_vector_type(8)));
typedef unsigned short u16x4 __attribute__((ext_vector_type(4)));

__device__ __forceinline__ unsigned short f2bf(float f) {
  unsigned int u = __float_as_uint(f);
  u += 0x7fffu + ((u >> 16) & 1u);   // round-to-nearest-even
  return (unsigned short)(u >> 16);
}
__device__ __forceinline__ float sigm(float v) { return 1.f / (1.f + __expf(-v)); }
__device__ __forceinline__ float tanh_f(float v) { return 1.f - 2.f / (1.f + __expf(2.f * v)); }

// ---------------- workspace layout (bytes) ----------------
// T   : 0        .. 2097152   bf16 [4096][256]   (stage1 out = [x@Ux , h@Uh])
// VC  : 2097152  .. 4194304   bf16 [4096][256]   wave-fragment-ordered V rows:
//        row r = jb*128 + w*32 + f*16 + c  ->  (gate g = f*2 + (c>>3),
//        j = jb*32 + w*8 + (c&7));  VC[r][k] = V_{x|h}[g*H + j][k]
// UTX : 4194304  .. 4325376   bf16 [128][512]    U_x^T
// UTH : 4325376  .. 4587520   bf16 [128][1024]   U_h^T
// CX  : 4587520  .. 4595712   f32  [4][512]      corr_x
// CH  : 4595712  .. 4612096   f32  [4][1024]     corr_h
// BC  : 4612096  .. 4628480   f32  [4096]        b_x + b_h

__global__ __launch_bounds__(256) void prep_kernel(
    const float* __restrict__ Ux, const float* __restrict__ Uh,
    const float* __restrict__ Vx, const float* __restrict__ Vh,
    const float* __restrict__ bx, const float* __restrict__ bh,
    unsigned short* __restrict__ VC, unsigned short* __restrict__ UTX,
    unsigned short* __restrict__ UTH, float* __restrict__ CX,
    float* __restrict__ CH, float* __restrict__ BC)
{
  int tid = blockIdx.x * 256 + threadIdx.x;
  if (tid < 131072) {                       // VC: fragment-ordered + bf16, 8 elems/thread
    int row = tid >> 5, kc = tid & 31, k = kc * 8;
    int jb = row >> 7;                      // 0..31 (32 j each)
    int t7 = row & 127;
    int w = t7 >> 5, f = (t7 >> 4) & 1, cc = t7 & 15;
    int g = f * 2 + (cc >> 3);
    int j = jb * 32 + w * 8 + (cc & 7);
    int vrow = g * HH + j;
    const float* src = (k < 128) ? (Vx + vrow * RR + k) : (Vh + vrow * RR + (k - 128));
    f32x4 a = *(const f32x4*)src;
    f32x4 b = *(const f32x4*)(src + 4);
    u16x8 o;
    o[0]=f2bf(a[0]); o[1]=f2bf(a[1]); o[2]=f2bf(a[2]); o[3]=f2bf(a[3]);
    o[4]=f2bf(b[0]); o[5]=f2bf(b[1]); o[6]=f2bf(b[2]); o[7]=f2bf(b[3]);
    *(u16x8*)(VC + row * 256 + k) = o;
  } else if (tid < 139264) {                // UTX: transpose U_x -> [n][k] bf16
    int idx = tid - 131072;
    int n = idx & 127, k = (idx >> 7) * 8;
    u16x8 o;
    #pragma unroll
    for (int e = 0; e < 8; ++e) o[e] = f2bf(Ux[(k + e) * RR + n]);
    *(u16x8*)(UTX + n * II + k) = o;
  } else if (tid < 155648) {                // UTH: transpose U_h -> [n][k] bf16
    int idx = tid - 139264;
    int n = idx & 127, k = (idx >> 7) * 8;
    u16x8 o;
    #pragma unroll
    for (int e = 0; e < 8; ++e) o[e] = f2bf(Uh[(k + e) * RR + n]);
    *(u16x8*)(UTH + n * HH + k) = o;
  } else if (tid < 157696) {                // corr_x[g][i]
    int idx = tid - 155648;
    int g = idx >> 9, i = idx & 511;
    const float* u = Ux + i * RR;
    const float* v = Vx + (g * HH + i) * RR;
    float s = 0.f;
    #pragma unroll 8
    for (int r4 = 0; r4 < 32; ++r4) {
      f32x4 uu = *(const f32x4*)(u + r4 * 4);
      f32x4 vv = *(const f32x4*)(v + r4 * 4);
      s += uu[0]*vv[0] + uu[1]*vv[1] + uu[2]*vv[2] + uu[3]*vv[3];
    }
    CX[g * II + i] = s;
  } else if (tid < 161792) {                // corr_h[g][j]
    int idx = tid - 157696;
    int g = idx >> 10, j = idx & 1023;
    const float* u = Uh + j * RR;
    const float* v = Vh + (g * HH + j) * RR;
    float s = 0.f;
    #pragma unroll 8
    for (int r4 = 0; r4 < 32; ++r4) {
      f32x4 uu = *(const f32x4*)(u + r4 * 4);
      f32x4 vv = *(const f32x4*)(v + r4 * 4);
      s += uu[0]*vv[0] + uu[1]*vv[1] + uu[2]*vv[2] + uu[3]*vv[3];
    }
    CH[g * HH + j] = s;
  } else if (tid < 165888) {                // combined bias
    int n = tid - 161792;
    BC[n] = bx[n] + bh[n];
  }
}

// ---- stage1 v3: 8-wave K-split, all A-loads issued up-front ----
template<int K, int NKS>
__device__ __forceinline__ void s1_core(
    const float* __restrict__ src, const unsigned short* __restrict__ Ut,
    unsigned short* __restrict__ T, float* __restrict__ Red,
    int b0, int p, int t)
{
  int l = t & 63, w = t >> 6;              // 8 waves, each owns K/8
  int row = l & 15, kof = (l >> 4) * 8;
  int kc0 = w * (K / 8);
  const float* ap = src + (b0 + row) * K + kc0 + kof;
  const unsigned short* bp = Ut + row * K + kc0 + kof;

  // phase 1: issue ALL A loads (HBM) before any MFMA dependency chain
  f32x4 a0[NKS], a1[NKS];
  #pragma unroll
  for (int ks = 0; ks < NKS; ++ks) {
    a0[ks] = *(const f32x4*)(ap + ks * 32);
    a1[ks] = *(const f32x4*)(ap + ks * 32 + 4);
  }

  f32x4 acc[8];
  #pragma unroll
  for (int fi = 0; fi < 8; ++fi) acc[fi] = (f32x4){0.f, 0.f, 0.f, 0.f};

  #pragma unroll
  for (int ks = 0; ks < NKS; ++ks) {
    union { bf16x8 v; unsigned short u[8]; } af;
    af.u[0]=f2bf(a0[ks][0]); af.u[1]=f2bf(a0[ks][1]);
    af.u[2]=f2bf(a0[ks][2]); af.u[3]=f2bf(a0[ks][3]);
    af.u[4]=f2bf(a1[ks][0]); af.u[5]=f2bf(a1[ks][1]);
    af.u[6]=f2bf(a1[ks][2]); af.u[7]=f2bf(a1[ks][3]);
    #pragma unroll
    for (int fi = 0; fi < 8; ++fi) {
      bf16x8 bf = *(const bf16x8*)(bp + fi * 16 * K + ks * 32);
      acc[fi] = __builtin_amdgcn_mfma_f32_16x16x32_bf16(af.v, bf, acc[fi], 0, 0, 0);
    }
  }

  // partials -> LDS [8 waves][16 rows][132 cols]
  #pragma unroll
  for (int fi = 0; fi < 8; ++fi) {
    int n = fi * 16 + row;
    #pragma unroll
    for (int reg = 0; reg < 4; ++reg) {
      int m = (l >> 4) * 4 + reg;
      Red[(w * 16 + m) * 132 + n] = acc[fi][reg];
    }
  }
  __syncthreads();

  // reduce 8 partials: 512 thr x 4 cols
  int m = t >> 5, c4 = (t & 31) * 4;
  f32x4 s = (f32x4){0.f, 0.f, 0.f, 0.f};
  #pragma unroll
  for (int wp = 0; wp < 8; ++wp)
    s += *(const f32x4*)(Red + (wp * 16 + m) * 132 + c4);
  u16x4 o;
  o[0]=f2bf(s[0]); o[1]=f2bf(s[1]); o[2]=f2bf(s[2]); o[3]=f2bf(s[3]);
  *(u16x4*)(T + (b0 + m) * 256 + p * 128 + c4) = o;
}

__global__ __launch_bounds__(512) void stage1_kernel(
    const float* __restrict__ x, const float* __restrict__ h,
    const unsigned short* __restrict__ UTX, const unsigned short* __restrict__ UTH,
    unsigned short* __restrict__ T)
{
  __shared__ alignas(16) float Red[8 * 16 * 132];   // 67584 B
  int t = threadIdx.x;
  int mb = blockIdx.x & 255;
  if (blockIdx.x < 256) s1_core<II, II / 256>(x, UTX, T, Red, mb * 16, 0, t);
  else                  s1_core<HH, HH / 256>(h, UTH, T, Red, mb * 16, 1, t);
}

// ---- stage2 v6: 2-phase pipelined multi-tile blocks ----
// 512 blocks; block owns jb (fixed) + 4 consecutive mb tiles. Double-buffered
// 2x32KB LDS A-tiles (gload_lds, swizzled global source); B (VC) in regs
// loaded once; epilogue operands double-buffered in named reg sets.
__device__ __forceinline__ void s2_stage(unsigned short* Asb,
    const unsigned short* __restrict__ T, int b0, int t)
{
  #pragma unroll
  for (int p = 0; p < 8; ++p) {
    int G = p * 256 + t;
    int r = G >> 5, gl = G & 31;
    int gs = gl ^ (r & 7);
    const unsigned short* gp = T + (b0 + r) * 256 + gs * 8;
    __builtin_amdgcn_global_load_lds(
        (const __attribute__((address_space(1))) void*)gp,
        (__attribute__((address_space(3))) void*)(Asb + G * 8), 16, 0, 0);
  }
}

__device__ __forceinline__ void s2_pref(float (&hv)[8], float (&cv)[8], float (&xv)[8],
    const float* __restrict__ h, const float* __restrict__ c,
    const float* __restrict__ x, int b0, int hi, int ch, int jv, bool has_x)
{
  #pragma unroll
  for (int rf = 0; rf < 4; ++rf)
    #pragma unroll
    for (int rr = 0; rr < 2; ++rr) {
      int q = rf * 2 + rr;
      int b = b0 + rf * 16 + hi * 4 + ch * 2 + rr;
      hv[q] = h[b * HH + jv];
      cv[q] = c[b * HH + jv];
      xv[q] = has_x ? x[b * II + jv] : 0.f;
    }
}

__device__ __forceinline__ void s2_comp(const unsigned short* Asb,
    const bf16x8 (&bf0)[8], const bf16x8 (&bf1)[8],
    const float (&hv)[8], const float (&cv)[8], const float (&xv)[8],
    float dhv, float dxv, const f32x4& cxv, const f32x4& chv, const f32x4& bcv,
    int b0, int r16, int hi, int ch, int jv, bool has_x,
    float* __restrict__ out)
{
  const char* Ab = (const char*)Asb;
  int rbase = r16 * 512;
  #pragma unroll
  for (int rf = 0; rf < 4; ++rf) {
    f32x4 acc0 = (f32x4){0.f, 0.f, 0.f, 0.f};
    f32x4 acc1 = (f32x4){0.f, 0.f, 0.f, 0.f};
    #pragma unroll
    for (int ks = 0; ks < 8; ++ks) {
      int gsw = ((ks * 4 + hi) ^ (r16 & 7)) * 16;
      bf16x8 a = *(const bf16x8*)(Ab + rf * 8192 + rbase + gsw);
      acc0 = __builtin_amdgcn_mfma_f32_16x16x32_bf16(a, bf0[ks], acc0, 0, 0, 0);
      acc1 = __builtin_amdgcn_mfma_f32_16x16x32_bf16(a, bf1[ks], acc1, 0, 0, 0);
    }
    #pragma unroll
    for (int rr = 0; rr < 2; ++rr) {
      int q = rf * 2 + rr;
      float keep0 = ch ? acc0[2 + rr] : acc0[rr];
      float send0 = ch ? acc0[rr] : acc0[2 + rr];
      float keep1 = ch ? acc1[2 + rr] : acc1[rr];
      float send1 = ch ? acc1[rr] : acc1[2 + rr];
      float recv0 = __shfl_xor(send0, 8);
      float recv1 = __shfl_xor(send1, 8);
      float p0 = ch ? recv0 : keep0;   // gate i
      float p1 = ch ? keep0 : recv0;   // gate f
      float p2 = ch ? recv1 : keep1;   // gate o
      float p3 = ch ? keep1 : recv1;   // gate n
      int b = b0 + rf * 16 + hi * 4 + ch * 2 + rr;
      float hvq = hv[q], cvq = cv[q];
      float addv = dhv * hvq;
      if (has_x) {
        float xvq = xv[q];
        addv += dxv * xvq;
        p0 -= xvq * cxv[0]; p1 -= xvq * cxv[1];
        p2 -= xvq * cxv[2]; p3 -= xvq * cxv[3];
      }
      p0 += bcv[0] + addv - hvq * chv[0];
      p1 += bcv[1] + addv - hvq * chv[1];
      p2 += bcv[2] + addv - hvq * chv[2];
      p3 += bcv[3] + addv - hvq * chv[3];
      float ig = sigm(p0);
      float fg = sigm(p1);
      float og = sigm(p2);
      float ng = tanh_f(p3);
      float cn = fg * cvq + ig * ng;
      float hn = og * tanh_f(cn);
      out[b * HH + jv] = hn;
      out[BB * HH + b * HH + jv] = cn;
    }
  }
}

#define S2_SYNC() do { \
    asm volatile("s_waitcnt vmcnt(0)" ::: "memory"); \
    __syncthreads(); \
  } while (0)

__global__ __launch_bounds__(256) void stage2_kernel(
    const unsigned short* __restrict__ T, const unsigned short* __restrict__ VC,
    const float* __restrict__ CX, const float* __restrict__ CH, const float* __restrict__ BC,
    const float* __restrict__ x, const float* __restrict__ h, const float* __restrict__ c,
    const float* __restrict__ dx, const float* __restrict__ dh,
    float* __restrict__ out)
{
  __shared__ alignas(16) unsigned short As0[64 * 256];   // 32 KB
  __shared__ alignas(16) unsigned short As1[64 * 256];   // 32 KB
  int t = threadIdx.x, l = t & 63, w = t >> 6;
  int xcd = blockIdx.x & 7, i = blockIdx.x >> 3;   // 512 = 8 xcd * 4 jbq * 16 ms
  int jb = xcd * 4 + (i >> 4);
  int ms = i & 15;
  int j0 = jb * 32;
  int r16 = l & 15, hi = l >> 4, koff = hi * 8, ch = (l >> 3) & 1;
  int jv = j0 + w * 8 + (l & 7);
  bool has_x = (j0 < II);
  int mb0 = ms * 4;                                 // 4 consecutive mb tiles

  // prologue: stage tile0 + epilogue operands for tile0
  s2_stage(As0, T, (mb0 + 0) * 64, t);
  float hA[8], cA[8], xA[8], hB[8], cB[8], xB[8];
  s2_pref(hA, cA, xA, h, c, x, (mb0 + 0) * 64, hi, ch, jv, has_x);

  // B fragments (once per block)
  const unsigned short* vp = VC + (jb * 128 + w * 32 + r16) * 256 + koff;
  bf16x8 bf0[8], bf1[8];
  #pragma unroll
  for (int ks = 0; ks < 8; ++ks) {
    bf0[ks] = *(const bf16x8*)(vp + ks * 32);
    bf1[ks] = *(const bf16x8*)(vp + 16 * 256 + ks * 32);
  }

  // per-j constants
  float dhv = dh[jv];
  float dxv = has_x ? dx[jv] : 0.f;
  f32x4 cxv = (f32x4){0.f, 0.f, 0.f, 0.f}, chv, bcv;
  if (has_x) {
    cxv[0] = CX[jv]; cxv[1] = CX[II + jv];
    cxv[2] = CX[2 * II + jv]; cxv[3] = CX[3 * II + jv];
  }
  chv[0] = CH[jv]; chv[1] = CH[HH + jv];
  chv[2] = CH[2 * HH + jv]; chv[3] = CH[3 * HH + jv];
  bcv[0] = BC[jv]; bcv[1] = BC[HH + jv];
  bcv[2] = BC[2 * HH + jv]; bcv[3] = BC[3 * HH + jv];

  S2_SYNC();

  // tile 0: stage tile1, compute tile0
  s2_stage(As1, T, (mb0 + 1) * 64, t);
  s2_pref(hB, cB, xB, h, c, x, (mb0 + 1) * 64, hi, ch, jv, has_x);
  s2_comp(As0, bf0, bf1, hA, cA, xA, dhv, dxv, cxv, chv, bcv,
          (mb0 + 0) * 64, r16, hi, ch, jv, has_x, out);
  S2_SYNC();

  // tile 1: stage tile2, compute tile1
  s2_stage(As0, T, (mb0 + 2) * 64, t);
  s2_pref(hA, cA, xA, h, c, x, (mb0 + 2) * 64, hi, ch, jv, has_x);
  s2_comp(As1, bf0, bf1, hB, cB, xB, dhv, dxv, cxv, chv, bcv,
          (mb0 + 1) * 64, r16, hi, ch, jv, has_x, out);
  S2_SYNC();

  // tile 2: stage tile3, compute tile2
  s2_stage(As1, T, (mb0 + 3) * 64, t);
  s2_pref(hB, cB, xB, h, c, x, (mb0 + 3) * 64, hi, ch, jv, has_x);
  s2_comp(As0, bf0, bf1, hA, cA, xA, dhv, dxv, cxv, chv, bcv,
          (mb0 + 2) * 64, r16, hi, ch, jv, has_x, out);
  S2_SYNC();

  // tile 3: compute only
  s2_comp(As1, bf0, bf1, hB, cB, xB, dhv, dxv, cxv, chv, bcv,
          (mb0 + 3) * 64, r16, hi, ch, jv, has_x, out);
}

extern "C" void kernel_launch(void* const* d_in, const int* in_sizes, int n_in,
                              void* d_out, int out_size, void* d_ws, size_t ws_size,
                              hipStream_t stream) {
  const float* x  = (const float*)d_in[0];
  const float* h  = (const float*)d_in[1];
  const float* c  = (const float*)d_in[2];
  const float* Ux = (const float*)d_in[3];
  const float* Uh = (const float*)d_in[4];
  const float* Vx = (const float*)d_in[5];
  const float* Vh = (const float*)d_in[6];
  const float* bx = (const float*)d_in[7];
  const float* bh = (const float*)d_in[8];
  const float* dx = (const float*)d_in[9];
  const float* dh = (const float*)d_in[10];
  char* ws = (char*)d_ws;
  unsigned short* T   = (unsigned short*)(ws + 0);
  unsigned short* VC  = (unsigned short*)(ws + 2097152);
  unsigned short* UTX = (unsigned short*)(ws + 4194304);
  unsigned short* UTH = (unsigned short*)(ws + 4325376);
  float* CX = (float*)(ws + 4587520);
  float* CH = (float*)(ws + 4595712);
  float* BC = (float*)(ws + 4612096);
  float* out = (float*)d_out;

  prep_kernel<<<648, 256, 0, stream>>>(Ux, Uh, Vx, Vh, bx, bh, VC, UTX, UTH, CX, CH, BC);
  stage1_kernel<<<512, 512, 0, stream>>>(x, h, UTX, UTH, T);
  stage2_kernel<<<512, 256, 0, stream>>>(T, VC, CX, CH, BC, x, h, c, dx, dh, out);
}